// Round 8
// baseline (114.560 us; speedup 1.0000x reference)
//
#include <hip/hip_runtime.h>

#define NROWS 8192
#define DDIM  256
#define NBINS 129

typedef float f32x4 __attribute__((ext_vector_type(4)));
typedef short bf16x8 __attribute__((ext_vector_type(8)));

__device__ __forceinline__ float wave_red(float v) {
#pragma unroll
    for (int m = 32; m; m >>= 1) v += __shfl_xor(v, m, 64);
    return v;
}

__device__ __forceinline__ unsigned bfbits(float f) {
    union { float f; unsigned u; } v; v.f = f;
    return (v.u + 0x7FFFu + ((v.u >> 16) & 1u)) >> 16;
}

__device__ __forceinline__ void gload_lds16(const void* g, void* l) {
    __builtin_amdgcn_global_load_lds((const __attribute__((address_space(1))) void*)g,
                                     (__attribute__((address_space(3))) void*)l,
                                     16, 0, 0);
}

// ---------------------------------------------------------------------------
// Kernel 1: DFT basis, transposed layout basisT[288][256] bf16.
// rows 0..128: cos(2*pi*n*k/256); rows 144..272: sin; others zero.
// ---------------------------------------------------------------------------
__global__ __launch_bounds__(256) void k_basis(unsigned short* __restrict__ basisT) {
    const int n = blockIdx.x;    // 0..287
    const int k = threadIdx.x;   // 0..255
    float v = 0.0f;
    const float step = 0.0245436926f;  // 2*pi/256
    if (n < 129)                  v = cosf(step * (float)((n * k) & 255));
    else if (n >= 144 && n < 273) v = sinf(step * (float)(((n - 144) * k) & 255));
    basisT[n * DDIM + k] = (unsigned short)bfbits(v);
}

// ---------------------------------------------------------------------------
// Kernel 2 (fused row+dft): 16 rows/block.
//  phase 1: coalesced read; spatial MSE + row norms
//  phase 2: normalized bf16 write
//  phase 3: A-fragments re-read from L2-hot global
//  phase 4: DFT via MFMA vs basisT; magnitudes; frequency MSE partial
// ---------------------------------------------------------------------------
__global__ __launch_bounds__(256) void k_prep(const float* __restrict__ clean,
                                              const float* __restrict__ turb,
                                              const unsigned short* __restrict__ basisT,
                                              unsigned short* __restrict__ cnb,
                                              unsigned short* __restrict__ tnb,
                                              float* __restrict__ spat_part,
                                              float* __restrict__ freq_part) {
    __shared__ float xch[2][2][16][132];   // [src][trig][row][bin] cr/ci  (33 KB)
    __shared__ float invn[16][2];
    __shared__ float sp4[4], rbuf[4];

    const int t    = threadIdx.x;
    const int w    = t >> 6;
    const int lane = t & 63;
    const int rb   = blockIdx.x * 16;

    // ---- phase 1: coalesced load; per-row norms; spatial partial ----
    float4 xc4[4], xt4[4];
    float dsq = 0.0f;
#pragma unroll
    for (int q = 0; q < 4; ++q) {
        const int row = q * 4 + w;           // wave w owns row q*4+w
        const float* pc = clean + (rb + row) * DDIM + lane * 4;
        const float* pt = turb  + (rb + row) * DDIM + lane * 4;
        xc4[q] = *(const float4*)pc;
        xt4[q] = *(const float4*)pt;
        const float4 a = xc4[q], b = xt4[q];
        dsq += (a.x - b.x) * (a.x - b.x) + (a.y - b.y) * (a.y - b.y)
             + (a.z - b.z) * (a.z - b.z) + (a.w - b.w) * (a.w - b.w);
        float nsc = a.x * a.x + a.y * a.y + a.z * a.z + a.w * a.w;
        float nst = b.x * b.x + b.y * b.y + b.z * b.z + b.w * b.w;
        nsc = wave_red(nsc);
        nst = wave_red(nst);
        if (lane == 0) {
            invn[row][0] = 1.0f / fmaxf(sqrtf(nsc), 1e-12f);
            invn[row][1] = 1.0f / fmaxf(sqrtf(nst), 1e-12f);
        }
    }
    dsq = wave_red(dsq);
    if (lane == 0) sp4[w] = dsq;
    __syncthreads();

    // ---- phase 2: normalized bf16 writes (8B coalesced stores) ----
#pragma unroll
    for (int q = 0; q < 4; ++q) {
        const int row = q * 4 + w;
        const float ic = invn[row][0], it = invn[row][1];
        const float4 a = xc4[q], b = xt4[q];
        uint2 pc, pt;
        pc.x = bfbits(a.x * ic) | (bfbits(a.y * ic) << 16);
        pc.y = bfbits(a.z * ic) | (bfbits(a.w * ic) << 16);
        pt.x = bfbits(b.x * it) | (bfbits(b.y * it) << 16);
        pt.y = bfbits(b.z * it) | (bfbits(b.w * it) << 16);
        *(uint2*)(cnb + (rb + row) * DDIM + lane * 4) = pc;
        *(uint2*)(tnb + (rb + row) * DDIM + lane * 4) = pt;
    }

    // ---- phase 3: A-fragments from L2-hot global ----
    const int srcw = w & 1;         // 0 clean, 1 turb
    const int trig = w >> 1;        // 0 cos, 1 sin
    bf16x8 a[8];
    {
        const float* src = srcw ? turb : clean;
        const float* rowp = src + (rb + (lane & 15)) * DDIM + ((lane >> 4) << 3);
#pragma unroll
        for (int kk = 0; kk < 8; ++kk) {
            const float4 lo = *(const float4*)(rowp + kk * 32);
            const float4 hi = *(const float4*)(rowp + kk * 32 + 4);
            bf16x8 tv;
            tv[0] = (short)bfbits(lo.x); tv[1] = (short)bfbits(lo.y);
            tv[2] = (short)bfbits(lo.z); tv[3] = (short)bfbits(lo.w);
            tv[4] = (short)bfbits(hi.x); tv[5] = (short)bfbits(hi.y);
            tv[6] = (short)bfbits(hi.z); tv[7] = (short)bfbits(hi.w);
            a[kk] = tv;
        }
    }

    // ---- phase 4: DFT MFMAs ----
    const unsigned short* bbase = basisT + (trig * 144 + (lane & 15)) * DDIM
                                + ((lane >> 4) << 3);
    const int lrow = (lane >> 4) << 2;
#pragma unroll 1
    for (int n = 0; n < 9; ++n) {
        f32x4 acc = (f32x4){0.f, 0.f, 0.f, 0.f};
#pragma unroll
        for (int kk = 0; kk < 8; ++kk) {
            bf16x8 b = *(const bf16x8*)(bbase + n * 16 * DDIM + kk * 32);
            acc = __builtin_amdgcn_mfma_f32_16x16x32_bf16(a[kk], b, acc, 0, 0, 0);
        }
        const int bin = n * 16 + (lane & 15);
        if (bin <= 128) {   // GUARD: n=8 covers bins 128..143; only 128 is real.
#pragma unroll
            for (int rr = 0; rr < 4; ++rr)
                xch[srcw][trig][lrow + rr][bin] = acc[rr];
        }
    }
    __syncthreads();

    // block reduce of (|fft_c| - |fft_t|)^2 over 16 rows x 129 bins
    {
        const int rr = t >> 4;
        float s = 0.0f;
        for (int b = (t & 15); b < NBINS; b += 16) {
            const float crc = xch[0][0][rr][b], cic = xch[0][1][rr][b];
            const float crt = xch[1][0][rr][b], cit = xch[1][1][rr][b];
            const float d = sqrtf(crc * crc + cic * cic)
                          - sqrtf(crt * crt + cit * cit);
            s += d * d;
        }
        s = wave_red(s);
        if (lane == 0) rbuf[w] = s;
    }
    __syncthreads();
    if (t == 0) {
        freq_part[blockIdx.x] = rbuf[0] + rbuf[1] + rbuf[2] + rbuf[3];
        spat_part[blockIdx.x] = sp4[0] + sp4[1] + sp4[2] + sp4[3];
    }
}

// ---------------------------------------------------------------------------
// Kernel 3: 128x128 bf16 MFMA GEMM. Single-buffer LDS, swizzled staging,
// supertile XCD swizzle, register-lean inner loop. PLAIN launch bounds
// (no forced occupancy: round-7 showed (256,4) spills ~16 regs -> 70 MB
// scratch traffic; natural 3 waves/SIMD with zero spill is faster).
// ---------------------------------------------------------------------------
#define BM 128
#define BN 128
#define BK 64

__global__ __launch_bounds__(256) void k_gemm(const unsigned short* __restrict__ cnb,
                                              const unsigned short* __restrict__ tnb,
                                              const int* __restrict__ sid,
                                              float* __restrict__ pall,
                                              float* __restrict__ ppos) {
    __shared__ unsigned short As[BM][BK];
    __shared__ unsigned short Bs[BN][BK];
    __shared__ float ps[2][BM][2];          // [colhalf][row][all|pos]
    __shared__ int sidI[BM], sidJ[BN];

    // Supertile XCD swizzle: xcd = bid&7 owns ib band [xcd*8, xcd*8+8).
    // Within XCD, walk 8x8 (ib x jb) supertiles -> ~1 MB working set per
    // supertile, fits 4 MB per-XCD L2. Bijective (4096%8==0).
    const int bid = blockIdx.x;
    const int xcd = bid & 7;
    const int q   = bid >> 3;            // 0..511
    const int grp = q >> 6;              // jb supertile group 0..7
    const int r   = q & 63;
    const int ib  = xcd * 8 + (r >> 3);
    const int jb  = grp * 8 + (r & 7);
    const int i0  = ib * BM;
    const int j0  = jb * BN;

    const int t = threadIdx.x;
    if (t < 128) sidI[t] = sid[i0 + t];
    else         sidJ[t - 128] = sid[j0 + t - 128];

    const int wid  = t >> 6;
    const int lane = t & 63;
    const int wrow = (wid >> 1) * 64;
    const int wcol = (wid & 1) * 64;
    const int rx   = lane & 7;

    f32x4 acc[4][4];
#pragma unroll
    for (int m = 0; m < 4; ++m)
#pragma unroll
        for (int n = 0; n < 4; ++n)
            acc[m][n] = (f32x4){0.f, 0.f, 0.f, 0.f};

    for (int kt = 0; kt < DDIM / BK; ++kt) {
        // stage: linear LDS dest, inverse-swizzled global source
#pragma unroll
        for (int it = 0; it < 4; ++it) {
            const int g  = it * 256 + t;          // 16B granule 0..1023
            const int rr = g >> 3;
            const int sl = g & 7;
            const int sc = ((sl ^ (rr & 7)) << 3);
            gload_lds16(cnb + (i0 + rr) * DDIM + kt * BK + sc,
                        (char*)&As[0][0] + g * 16);
            gload_lds16(tnb + (j0 + rr) * DDIM + kt * BK + sc,
                        (char*)&Bs[0][0] + g * 16);
        }
        __syncthreads();   // drains vmcnt before reads
#pragma unroll
        for (int kk = 0; kk < BK / 32; ++kk) {
            const int kslot = kk * 4 + (lane >> 4);
            bf16x8 bfr[4];
#pragma unroll
            for (int n = 0; n < 4; ++n) {
                const int row = wcol + n * 16 + (lane & 15);
                bfr[n] = *(const bf16x8*)((const char*)&Bs[0][0]
                          + row * 128 + ((kslot ^ rx) << 4));
            }
#pragma unroll
            for (int m = 0; m < 4; ++m) {
                const int row = wrow + m * 16 + (lane & 15);
                const bf16x8 af = *(const bf16x8*)((const char*)&As[0][0]
                          + row * 128 + ((kslot ^ rx) << 4));
#pragma unroll
                for (int n = 0; n < 4; ++n)
                    acc[m][n] = __builtin_amdgcn_mfma_f32_16x16x32_bf16(
                        af, bfr[n], acc[m][n], 0, 0, 0);
            }
        }
        __syncthreads();   // all reads done before next stage overwrites
    }

    // epilogue: exp2, mask, 16-lane row-reduce, LDS combine, per-block store
    const float C = (1.0f / 0.07f) * 1.442695041f;   // invT * log2(e)
#pragma unroll
    for (int m = 0; m < 4; ++m) {
        const int rbase = wrow + m * 16 + ((lane >> 4) << 2);
        int si[4];
#pragma unroll
        for (int r2 = 0; r2 < 4; ++r2) si[r2] = sidI[rbase + r2];
        float rs_all[4] = {0.f, 0.f, 0.f, 0.f};
        float rs_pos[4] = {0.f, 0.f, 0.f, 0.f};
#pragma unroll
        for (int n = 0; n < 4; ++n) {
            const int col = wcol + n * 16 + (lane & 15);
            const int sj = sidJ[col];
#pragma unroll
            for (int r2 = 0; r2 < 4; ++r2) {
                float e = exp2f(acc[m][n][r2] * C);
                rs_all[r2] += e;
                rs_pos[r2] += (si[r2] == sj) ? e : 0.0f;
            }
        }
#pragma unroll
        for (int msk = 1; msk < 16; msk <<= 1) {
#pragma unroll
            for (int r2 = 0; r2 < 4; ++r2) {
                rs_all[r2] += __shfl_xor(rs_all[r2], msk, 64);
                rs_pos[r2] += __shfl_xor(rs_pos[r2], msk, 64);
            }
        }
        if ((lane & 15) == 0) {
#pragma unroll
            for (int r2 = 0; r2 < 4; ++r2) {
                ps[wid & 1][rbase + r2][0] = rs_all[r2];
                ps[wid & 1][rbase + r2][1] = rs_pos[r2];
            }
        }
    }
    __syncthreads();
    if (t < BM) {
        const float sa = ps[0][t][0] + ps[1][t][0];
        const float sp = ps[0][t][1] + ps[1][t][1];
        pall[jb * NROWS + i0 + t] = sa;
        ppos[jb * NROWS + i0 + t] = sp;
    }
}

// ---------------------------------------------------------------------------
// Kernel 4: per-row sum over 64 j-block partials + log terms.
// ---------------------------------------------------------------------------
__global__ __launch_bounds__(256) void k_red(const float* __restrict__ pall,
                                             const float* __restrict__ ppos,
                                             float* __restrict__ contrib) {
    __shared__ float red[256];
    const int row = blockIdx.x * 256 + threadIdx.x;
    float sa = 0.0f, sp = 0.0f;
    for (int jb = 0; jb < 64; ++jb) {
        sa += pall[jb * NROWS + row];
        sp += ppos[jb * NROWS + row];
    }
    red[threadIdx.x] = logf(sa + 1e-8f) - logf(sp);
    __syncthreads();
#pragma unroll
    for (int s = 128; s > 0; s >>= 1) {
        if (threadIdx.x < s) red[threadIdx.x] += red[threadIdx.x + s];
        __syncthreads();
    }
    if (threadIdx.x == 0) contrib[blockIdx.x] = red[0];
}

// ---------------------------------------------------------------------------
// Kernel 5: fold all partials -> 4 outputs
// ---------------------------------------------------------------------------
__global__ __launch_bounds__(256) void k_final(const float* __restrict__ spat_part,
                                               const float* __restrict__ freq_part,
                                               const float* __restrict__ contrib,
                                               float* __restrict__ out) {
    __shared__ float reda[256], redb[256], redc[256];
    float a = 0.0f, b = 0.0f, c = 0.0f;
    for (int i = threadIdx.x; i < 512; i += 256) {
        a += spat_part[i];
        b += freq_part[i];
    }
    if (threadIdx.x < 32) c = contrib[threadIdx.x];
    reda[threadIdx.x] = a; redb[threadIdx.x] = b; redc[threadIdx.x] = c;
    __syncthreads();
#pragma unroll
    for (int s = 128; s > 0; s >>= 1) {
        if (threadIdx.x < s) {
            reda[threadIdx.x] += reda[threadIdx.x + s];
            redb[threadIdx.x] += redb[threadIdx.x + s];
            redc[threadIdx.x] += redc[threadIdx.x + s];
        }
        __syncthreads();
    }
    if (threadIdx.x == 0) {
        float spatial = reda[0] / (float)(NROWS * DDIM);
        float frequency = redb[0] / (float)(NROWS * NBINS);
        float contrastive = redc[0] / (float)NROWS;
        out[0] = spatial + frequency + 0.5f * contrastive;
        out[1] = spatial;
        out[2] = frequency;
        out[3] = contrastive;
    }
}

// ---------------------------------------------------------------------------
extern "C" void kernel_launch(void* const* d_in, const int* in_sizes, int n_in,
                              void* d_out, int out_size, void* d_ws, size_t ws_size,
                              hipStream_t stream) {
    const float* clean = (const float*)d_in[0];
    const float* turb  = (const float*)d_in[1];
    const int*   sids  = (const int*)d_in[2];

    char* ws = (char*)d_ws;
    unsigned short* cnb    = (unsigned short*)ws;                      // 4 MB
    unsigned short* tnb    = (unsigned short*)(ws + 4194304);          // 4 MB
    unsigned short* basisT = (unsigned short*)(ws + 8388608);          // 147 KB
    float* pall      = (float*)(ws + 8650752);                         // 2 MB
    float* ppos      = (float*)(ws + 10747904);                        // 2 MB
    float* spat_part = (float*)(ws + 12845056);                        // 2 KB
    float* freq_part = (float*)(ws + 12849152);                        // 2 KB
    float* contrib   = (float*)(ws + 12853248);                        // 128 B

    hipLaunchKernelGGL(k_basis, dim3(288), dim3(256), 0, stream, basisT);
    hipLaunchKernelGGL(k_prep, dim3(NROWS / 16), dim3(256), 0, stream,
                       clean, turb, basisT, cnb, tnb, spat_part, freq_part);
    hipLaunchKernelGGL(k_gemm, dim3(4096), dim3(256), 0, stream,
                       cnb, tnb, sids, pall, ppos);
    hipLaunchKernelGGL(k_red, dim3(NROWS / 256), dim3(256), 0, stream,
                       pall, ppos, contrib);
    hipLaunchKernelGGL(k_final, dim3(1), dim3(256), 0, stream,
                       spat_part, freq_part, contrib, (float*)d_out);
}

// Round 9
// 111.978 us; speedup vs baseline: 1.0231x; 1.0231x over previous
//
#include <hip/hip_runtime.h>

#define NROWS 8192
#define DDIM  256
#define NBINS 129

typedef float f32x4 __attribute__((ext_vector_type(4)));
typedef short bf16x8 __attribute__((ext_vector_type(8)));

__device__ __forceinline__ float wave_red(float v) {
#pragma unroll
    for (int m = 32; m; m >>= 1) v += __shfl_xor(v, m, 64);
    return v;
}

__device__ __forceinline__ unsigned bfbits(float f) {
    union { float f; unsigned u; } v; v.f = f;
    return (v.u + 0x7FFFu + ((v.u >> 16) & 1u)) >> 16;
}

__device__ __forceinline__ void gload_lds16(const void* g, void* l) {
    __builtin_amdgcn_global_load_lds((const __attribute__((address_space(1))) void*)g,
                                     (__attribute__((address_space(3))) void*)l,
                                     16, 0, 0);
}

// ---------------------------------------------------------------------------
// Kernel 1: DFT basis, transposed layout basisT[288][256] bf16.
// rows 0..128: cos(2*pi*n*k/256); rows 144..272: sin; others zero.
// ---------------------------------------------------------------------------
__global__ __launch_bounds__(256) void k_basis(unsigned short* __restrict__ basisT) {
    const int n = blockIdx.x;    // 0..287
    const int k = threadIdx.x;   // 0..255
    float v = 0.0f;
    const float step = 0.0245436926f;  // 2*pi/256
    if (n < 129)                  v = cosf(step * (float)((n * k) & 255));
    else if (n >= 144 && n < 273) v = sinf(step * (float)(((n - 144) * k) & 255));
    basisT[n * DDIM + k] = (unsigned short)bfbits(v);
}

// ---------------------------------------------------------------------------
// Kernel 2 (fused row+dft): 16 rows/block.
//  phase 1: coalesced read; spatial MSE + row norms
//  phase 2: normalized bf16 write
//  phase 3: A-fragments re-read from L2-hot global
//  phase 4: DFT via MFMA vs basisT; magnitudes; frequency MSE partial
// ---------------------------------------------------------------------------
__global__ __launch_bounds__(256) void k_prep(const float* __restrict__ clean,
                                              const float* __restrict__ turb,
                                              const unsigned short* __restrict__ basisT,
                                              unsigned short* __restrict__ cnb,
                                              unsigned short* __restrict__ tnb,
                                              float* __restrict__ spat_part,
                                              float* __restrict__ freq_part) {
    __shared__ float xch[2][2][16][132];   // [src][trig][row][bin] cr/ci  (33 KB)
    __shared__ float invn[16][2];
    __shared__ float sp4[4], rbuf[4];

    const int t    = threadIdx.x;
    const int w    = t >> 6;
    const int lane = t & 63;
    const int rb   = blockIdx.x * 16;

    // ---- phase 1: coalesced load; per-row norms; spatial partial ----
    float4 xc4[4], xt4[4];
    float dsq = 0.0f;
#pragma unroll
    for (int q = 0; q < 4; ++q) {
        const int row = q * 4 + w;           // wave w owns row q*4+w
        const float* pc = clean + (rb + row) * DDIM + lane * 4;
        const float* pt = turb  + (rb + row) * DDIM + lane * 4;
        xc4[q] = *(const float4*)pc;
        xt4[q] = *(const float4*)pt;
        const float4 a = xc4[q], b = xt4[q];
        dsq += (a.x - b.x) * (a.x - b.x) + (a.y - b.y) * (a.y - b.y)
             + (a.z - b.z) * (a.z - b.z) + (a.w - b.w) * (a.w - b.w);
        float nsc = a.x * a.x + a.y * a.y + a.z * a.z + a.w * a.w;
        float nst = b.x * b.x + b.y * b.y + b.z * b.z + b.w * b.w;
        nsc = wave_red(nsc);
        nst = wave_red(nst);
        if (lane == 0) {
            invn[row][0] = 1.0f / fmaxf(sqrtf(nsc), 1e-12f);
            invn[row][1] = 1.0f / fmaxf(sqrtf(nst), 1e-12f);
        }
    }
    dsq = wave_red(dsq);
    if (lane == 0) sp4[w] = dsq;
    __syncthreads();

    // ---- phase 2: normalized bf16 writes (8B coalesced stores) ----
#pragma unroll
    for (int q = 0; q < 4; ++q) {
        const int row = q * 4 + w;
        const float ic = invn[row][0], it = invn[row][1];
        const float4 a = xc4[q], b = xt4[q];
        uint2 pc, pt;
        pc.x = bfbits(a.x * ic) | (bfbits(a.y * ic) << 16);
        pc.y = bfbits(a.z * ic) | (bfbits(a.w * ic) << 16);
        pt.x = bfbits(b.x * it) | (bfbits(b.y * it) << 16);
        pt.y = bfbits(b.z * it) | (bfbits(b.w * it) << 16);
        *(uint2*)(cnb + (rb + row) * DDIM + lane * 4) = pc;
        *(uint2*)(tnb + (rb + row) * DDIM + lane * 4) = pt;
    }

    // ---- phase 3: A-fragments from L2-hot global ----
    const int srcw = w & 1;         // 0 clean, 1 turb
    const int trig = w >> 1;        // 0 cos, 1 sin
    bf16x8 a[8];
    {
        const float* src = srcw ? turb : clean;
        const float* rowp = src + (rb + (lane & 15)) * DDIM + ((lane >> 4) << 3);
#pragma unroll
        for (int kk = 0; kk < 8; ++kk) {
            const float4 lo = *(const float4*)(rowp + kk * 32);
            const float4 hi = *(const float4*)(rowp + kk * 32 + 4);
            bf16x8 tv;
            tv[0] = (short)bfbits(lo.x); tv[1] = (short)bfbits(lo.y);
            tv[2] = (short)bfbits(lo.z); tv[3] = (short)bfbits(lo.w);
            tv[4] = (short)bfbits(hi.x); tv[5] = (short)bfbits(hi.y);
            tv[6] = (short)bfbits(hi.z); tv[7] = (short)bfbits(hi.w);
            a[kk] = tv;
        }
    }

    // ---- phase 4: DFT MFMAs ----
    const unsigned short* bbase = basisT + (trig * 144 + (lane & 15)) * DDIM
                                + ((lane >> 4) << 3);
    const int lrow = (lane >> 4) << 2;
#pragma unroll 1
    for (int n = 0; n < 9; ++n) {
        f32x4 acc = (f32x4){0.f, 0.f, 0.f, 0.f};
#pragma unroll
        for (int kk = 0; kk < 8; ++kk) {
            bf16x8 b = *(const bf16x8*)(bbase + n * 16 * DDIM + kk * 32);
            acc = __builtin_amdgcn_mfma_f32_16x16x32_bf16(a[kk], b, acc, 0, 0, 0);
        }
        const int bin = n * 16 + (lane & 15);
        if (bin <= 128) {   // GUARD: n=8 covers bins 128..143; only 128 is real.
#pragma unroll
            for (int rr = 0; rr < 4; ++rr)
                xch[srcw][trig][lrow + rr][bin] = acc[rr];
        }
    }
    __syncthreads();

    // block reduce of (|fft_c| - |fft_t|)^2 over 16 rows x 129 bins
    {
        const int rr = t >> 4;
        float s = 0.0f;
        for (int b = (t & 15); b < NBINS; b += 16) {
            const float crc = xch[0][0][rr][b], cic = xch[0][1][rr][b];
            const float crt = xch[1][0][rr][b], cit = xch[1][1][rr][b];
            const float d = sqrtf(crc * crc + cic * cic)
                          - sqrtf(crt * crt + cit * cit);
            s += d * d;
        }
        s = wave_red(s);
        if (lane == 0) rbuf[w] = s;
    }
    __syncthreads();
    if (t == 0) {
        freq_part[blockIdx.x] = rbuf[0] + rbuf[1] + rbuf[2] + rbuf[3];
        spat_part[blockIdx.x] = sp4[0] + sp4[1] + sp4[2] + sp4[3];
    }
}

// ---------------------------------------------------------------------------
// Kernel 3: 128x128 bf16 MFMA GEMM. Round-6 inner-loop form (af[4]/bfr[4]
// preloaded arrays -> compiled to 72 VGPR, 28% occupancy) + supertile XCD
// swizzle (validated: FETCH 64->18.6 MB). Plain launch bounds (r7's (256,4)
// spilled ~16 regs -> 70 MB scratch traffic).
// ---------------------------------------------------------------------------
#define BM 128
#define BN 128
#define BK 64

__global__ __launch_bounds__(256) void k_gemm(const unsigned short* __restrict__ cnb,
                                              const unsigned short* __restrict__ tnb,
                                              const int* __restrict__ sid,
                                              float* __restrict__ pall,
                                              float* __restrict__ ppos) {
    __shared__ unsigned short As[BM][BK];
    __shared__ unsigned short Bs[BN][BK];
    __shared__ float ps[2][BM][2];          // [colhalf][row][all|pos]
    __shared__ int sidI[BM], sidJ[BN];

    // Supertile XCD swizzle: xcd = bid&7 owns ib band [xcd*8, xcd*8+8).
    // Within XCD, walk 8x8 (ib x jb) supertiles -> ~1 MB working set per
    // supertile, fits 4 MB per-XCD L2. Bijective (4096%8==0).
    const int bid = blockIdx.x;
    const int xcd = bid & 7;
    const int q   = bid >> 3;            // 0..511
    const int grp = q >> 6;              // jb supertile group 0..7
    const int r   = q & 63;
    const int ib  = xcd * 8 + (r >> 3);
    const int jb  = grp * 8 + (r & 7);
    const int i0  = ib * BM;
    const int j0  = jb * BN;

    const int t = threadIdx.x;
    if (t < 128) sidI[t] = sid[i0 + t];
    else         sidJ[t - 128] = sid[j0 + t - 128];

    const int wid  = t >> 6;
    const int lane = t & 63;
    const int wrow = (wid >> 1) * 64;
    const int wcol = (wid & 1) * 64;
    const int rx   = lane & 7;

    f32x4 acc[4][4];
#pragma unroll
    for (int m = 0; m < 4; ++m)
#pragma unroll
        for (int n = 0; n < 4; ++n)
            acc[m][n] = (f32x4){0.f, 0.f, 0.f, 0.f};

    for (int kt = 0; kt < DDIM / BK; ++kt) {
        // stage: linear LDS dest, inverse-swizzled global source
#pragma unroll
        for (int it = 0; it < 4; ++it) {
            const int g  = it * 256 + t;          // 16B granule 0..1023
            const int rr = g >> 3;
            const int sl = g & 7;
            const int sc = ((sl ^ (rr & 7)) << 3);
            gload_lds16(cnb + (i0 + rr) * DDIM + kt * BK + sc,
                        (char*)&As[0][0] + g * 16);
            gload_lds16(tnb + (j0 + rr) * DDIM + kt * BK + sc,
                        (char*)&Bs[0][0] + g * 16);
        }
        __syncthreads();   // drains vmcnt before reads
#pragma unroll
        for (int kk = 0; kk < BK / 32; ++kk) {
            const int kslot = kk * 4 + (lane >> 4);
            bf16x8 af[4], bfr[4];
#pragma unroll
            for (int m = 0; m < 4; ++m) {
                const int row = wrow + m * 16 + (lane & 15);
                af[m] = *(const bf16x8*)((const char*)&As[0][0]
                          + row * 128 + ((kslot ^ rx) << 4));
            }
#pragma unroll
            for (int n = 0; n < 4; ++n) {
                const int row = wcol + n * 16 + (lane & 15);
                bfr[n] = *(const bf16x8*)((const char*)&Bs[0][0]
                          + row * 128 + ((kslot ^ rx) << 4));
            }
#pragma unroll
            for (int m = 0; m < 4; ++m)
#pragma unroll
                for (int n = 0; n < 4; ++n)
                    acc[m][n] = __builtin_amdgcn_mfma_f32_16x16x32_bf16(
                        af[m], bfr[n], acc[m][n], 0, 0, 0);
        }
        __syncthreads();   // all reads done before next stage overwrites
    }

    // epilogue: exp2, mask, 16-lane row-reduce, LDS combine, per-block store
    const float C = (1.0f / 0.07f) * 1.442695041f;   // invT * log2(e)
#pragma unroll
    for (int m = 0; m < 4; ++m) {
        const int rbase = wrow + m * 16 + ((lane >> 4) << 2);
        int si[4];
#pragma unroll
        for (int r2 = 0; r2 < 4; ++r2) si[r2] = sidI[rbase + r2];
        float rs_all[4] = {0.f, 0.f, 0.f, 0.f};
        float rs_pos[4] = {0.f, 0.f, 0.f, 0.f};
#pragma unroll
        for (int n = 0; n < 4; ++n) {
            const int col = wcol + n * 16 + (lane & 15);
            const int sj = sidJ[col];
#pragma unroll
            for (int r2 = 0; r2 < 4; ++r2) {
                float e = exp2f(acc[m][n][r2] * C);
                rs_all[r2] += e;
                rs_pos[r2] += (si[r2] == sj) ? e : 0.0f;
            }
        }
#pragma unroll
        for (int msk = 1; msk < 16; msk <<= 1) {
#pragma unroll
            for (int r2 = 0; r2 < 4; ++r2) {
                rs_all[r2] += __shfl_xor(rs_all[r2], msk, 64);
                rs_pos[r2] += __shfl_xor(rs_pos[r2], msk, 64);
            }
        }
        if ((lane & 15) == 0) {
#pragma unroll
            for (int r2 = 0; r2 < 4; ++r2) {
                ps[wid & 1][rbase + r2][0] = rs_all[r2];
                ps[wid & 1][rbase + r2][1] = rs_pos[r2];
            }
        }
    }
    __syncthreads();
    if (t < BM) {
        const float sa = ps[0][t][0] + ps[1][t][0];
        const float sp = ps[0][t][1] + ps[1][t][1];
        pall[jb * NROWS + i0 + t] = sa;
        ppos[jb * NROWS + i0 + t] = sp;
    }
}

// ---------------------------------------------------------------------------
// Kernel 4: per-row sum over 64 j-block partials + log terms.
// ---------------------------------------------------------------------------
__global__ __launch_bounds__(256) void k_red(const float* __restrict__ pall,
                                             const float* __restrict__ ppos,
                                             float* __restrict__ contrib) {
    __shared__ float red[256];
    const int row = blockIdx.x * 256 + threadIdx.x;
    float sa = 0.0f, sp = 0.0f;
    for (int jb = 0; jb < 64; ++jb) {
        sa += pall[jb * NROWS + row];
        sp += ppos[jb * NROWS + row];
    }
    red[threadIdx.x] = logf(sa + 1e-8f) - logf(sp);
    __syncthreads();
#pragma unroll
    for (int s = 128; s > 0; s >>= 1) {
        if (threadIdx.x < s) red[threadIdx.x] += red[threadIdx.x + s];
        __syncthreads();
    }
    if (threadIdx.x == 0) contrib[blockIdx.x] = red[0];
}

// ---------------------------------------------------------------------------
// Kernel 5: fold all partials -> 4 outputs
// ---------------------------------------------------------------------------
__global__ __launch_bounds__(256) void k_final(const float* __restrict__ spat_part,
                                               const float* __restrict__ freq_part,
                                               const float* __restrict__ contrib,
                                               float* __restrict__ out) {
    __shared__ float reda[256], redb[256], redc[256];
    float a = 0.0f, b = 0.0f, c = 0.0f;
    for (int i = threadIdx.x; i < 512; i += 256) {
        a += spat_part[i];
        b += freq_part[i];
    }
    if (threadIdx.x < 32) c = contrib[threadIdx.x];
    reda[threadIdx.x] = a; redb[threadIdx.x] = b; redc[threadIdx.x] = c;
    __syncthreads();
#pragma unroll
    for (int s = 128; s > 0; s >>= 1) {
        if (threadIdx.x < s) {
            reda[threadIdx.x] += reda[threadIdx.x + s];
            redb[threadIdx.x] += redb[threadIdx.x + s];
            redc[threadIdx.x] += redc[threadIdx.x + s];
        }
        __syncthreads();
    }
    if (threadIdx.x == 0) {
        float spatial = reda[0] / (float)(NROWS * DDIM);
        float frequency = redb[0] / (float)(NROWS * NBINS);
        float contrastive = redc[0] / (float)NROWS;
        out[0] = spatial + frequency + 0.5f * contrastive;
        out[1] = spatial;
        out[2] = frequency;
        out[3] = contrastive;
    }
}

// ---------------------------------------------------------------------------
extern "C" void kernel_launch(void* const* d_in, const int* in_sizes, int n_in,
                              void* d_out, int out_size, void* d_ws, size_t ws_size,
                              hipStream_t stream) {
    const float* clean = (const float*)d_in[0];
    const float* turb  = (const float*)d_in[1];
    const int*   sids  = (const int*)d_in[2];

    char* ws = (char*)d_ws;
    unsigned short* cnb    = (unsigned short*)ws;                      // 4 MB
    unsigned short* tnb    = (unsigned short*)(ws + 4194304);          // 4 MB
    unsigned short* basisT = (unsigned short*)(ws + 8388608);          // 147 KB
    float* pall      = (float*)(ws + 8650752);                         // 2 MB
    float* ppos      = (float*)(ws + 10747904);                        // 2 MB
    float* spat_part = (float*)(ws + 12845056);                        // 2 KB
    float* freq_part = (float*)(ws + 12849152);                        // 2 KB
    float* contrib   = (float*)(ws + 12853248);                        // 128 B

    hipLaunchKernelGGL(k_basis, dim3(288), dim3(256), 0, stream, basisT);
    hipLaunchKernelGGL(k_prep, dim3(NROWS / 16), dim3(256), 0, stream,
                       clean, turb, basisT, cnb, tnb, spat_part, freq_part);
    hipLaunchKernelGGL(k_gemm, dim3(4096), dim3(256), 0, stream,
                       cnb, tnb, sids, pall, ppos);
    hipLaunchKernelGGL(k_red, dim3(NROWS / 256), dim3(256), 0, stream,
                       pall, ppos, contrib);
    hipLaunchKernelGGL(k_final, dim3(1), dim3(256), 0, stream,
                       spat_part, freq_part, contrib, (float*)d_out);
}

// Round 10
// 97.004 us; speedup vs baseline: 1.1810x; 1.1544x over previous
//
#include <hip/hip_runtime.h>

#define NROWS 8192
#define DDIM  256
#define NBINS 129

typedef float f32x4 __attribute__((ext_vector_type(4)));
typedef short bf16x8 __attribute__((ext_vector_type(8)));

__device__ __forceinline__ float wave_red(float v) {
#pragma unroll
    for (int m = 32; m; m >>= 1) v += __shfl_xor(v, m, 64);
    return v;
}

__device__ __forceinline__ unsigned bfbits(float f) {
    union { float f; unsigned u; } v; v.f = f;
    return (v.u + 0x7FFFu + ((v.u >> 16) & 1u)) >> 16;
}

__device__ __forceinline__ void gload_lds16(const void* g, void* l) {
    __builtin_amdgcn_global_load_lds((const __attribute__((address_space(1))) void*)g,
                                     (__attribute__((address_space(3))) void*)l,
                                     16, 0, 0);
}

// ---------------------------------------------------------------------------
// Kernel 1: DFT basis, transposed layout basisT[288][256] bf16.
// rows 0..128: cos(2*pi*n*k/256); rows 144..272: sin; others zero.
// ---------------------------------------------------------------------------
__global__ __launch_bounds__(256) void k_basis(unsigned short* __restrict__ basisT) {
    const int n = blockIdx.x;    // 0..287
    const int k = threadIdx.x;   // 0..255
    float v = 0.0f;
    const float step = 0.0245436926f;  // 2*pi/256
    if (n < 129)                  v = cosf(step * (float)((n * k) & 255));
    else if (n >= 144 && n < 273) v = sinf(step * (float)(((n - 144) * k) & 255));
    basisT[n * DDIM + k] = (unsigned short)bfbits(v);
}

// ---------------------------------------------------------------------------
// Kernel 2 (fused row+dft): 16 rows/block.
//  phase 1: coalesced read; spatial MSE + row norms
//  phase 2: normalized bf16 write
//  phase 3: A-fragments re-read from L2-hot global
//  phase 4: DFT via MFMA vs basisT; magnitudes; frequency MSE partial
// ---------------------------------------------------------------------------
__global__ __launch_bounds__(256) void k_prep(const float* __restrict__ clean,
                                              const float* __restrict__ turb,
                                              const unsigned short* __restrict__ basisT,
                                              unsigned short* __restrict__ cnb,
                                              unsigned short* __restrict__ tnb,
                                              float* __restrict__ spat_part,
                                              float* __restrict__ freq_part) {
    __shared__ float xch[2][2][16][132];   // [src][trig][row][bin] cr/ci  (33 KB)
    __shared__ float invn[16][2];
    __shared__ float sp4[4], rbuf[4];

    const int t    = threadIdx.x;
    const int w    = t >> 6;
    const int lane = t & 63;
    const int rb   = blockIdx.x * 16;

    // ---- phase 1: coalesced load; per-row norms; spatial partial ----
    float4 xc4[4], xt4[4];
    float dsq = 0.0f;
#pragma unroll
    for (int q = 0; q < 4; ++q) {
        const int row = q * 4 + w;           // wave w owns row q*4+w
        const float* pc = clean + (rb + row) * DDIM + lane * 4;
        const float* pt = turb  + (rb + row) * DDIM + lane * 4;
        xc4[q] = *(const float4*)pc;
        xt4[q] = *(const float4*)pt;
        const float4 a = xc4[q], b = xt4[q];
        dsq += (a.x - b.x) * (a.x - b.x) + (a.y - b.y) * (a.y - b.y)
             + (a.z - b.z) * (a.z - b.z) + (a.w - b.w) * (a.w - b.w);
        float nsc = a.x * a.x + a.y * a.y + a.z * a.z + a.w * a.w;
        float nst = b.x * b.x + b.y * b.y + b.z * b.z + b.w * b.w;
        nsc = wave_red(nsc);
        nst = wave_red(nst);
        if (lane == 0) {
            invn[row][0] = 1.0f / fmaxf(sqrtf(nsc), 1e-12f);
            invn[row][1] = 1.0f / fmaxf(sqrtf(nst), 1e-12f);
        }
    }
    dsq = wave_red(dsq);
    if (lane == 0) sp4[w] = dsq;
    __syncthreads();

    // ---- phase 2: normalized bf16 writes (8B coalesced stores) ----
#pragma unroll
    for (int q = 0; q < 4; ++q) {
        const int row = q * 4 + w;
        const float ic = invn[row][0], it = invn[row][1];
        const float4 a = xc4[q], b = xt4[q];
        uint2 pc, pt;
        pc.x = bfbits(a.x * ic) | (bfbits(a.y * ic) << 16);
        pc.y = bfbits(a.z * ic) | (bfbits(a.w * ic) << 16);
        pt.x = bfbits(b.x * it) | (bfbits(b.y * it) << 16);
        pt.y = bfbits(b.z * it) | (bfbits(b.w * it) << 16);
        *(uint2*)(cnb + (rb + row) * DDIM + lane * 4) = pc;
        *(uint2*)(tnb + (rb + row) * DDIM + lane * 4) = pt;
    }

    // ---- phase 3: A-fragments from L2-hot global ----
    const int srcw = w & 1;         // 0 clean, 1 turb
    const int trig = w >> 1;        // 0 cos, 1 sin
    bf16x8 a[8];
    {
        const float* src = srcw ? turb : clean;
        const float* rowp = src + (rb + (lane & 15)) * DDIM + ((lane >> 4) << 3);
#pragma unroll
        for (int kk = 0; kk < 8; ++kk) {
            const float4 lo = *(const float4*)(rowp + kk * 32);
            const float4 hi = *(const float4*)(rowp + kk * 32 + 4);
            bf16x8 tv;
            tv[0] = (short)bfbits(lo.x); tv[1] = (short)bfbits(lo.y);
            tv[2] = (short)bfbits(lo.z); tv[3] = (short)bfbits(lo.w);
            tv[4] = (short)bfbits(hi.x); tv[5] = (short)bfbits(hi.y);
            tv[6] = (short)bfbits(hi.z); tv[7] = (short)bfbits(hi.w);
            a[kk] = tv;
        }
    }

    // ---- phase 4: DFT MFMAs ----
    const unsigned short* bbase = basisT + (trig * 144 + (lane & 15)) * DDIM
                                + ((lane >> 4) << 3);
    const int lrow = (lane >> 4) << 2;
#pragma unroll 1
    for (int n = 0; n < 9; ++n) {
        f32x4 acc = (f32x4){0.f, 0.f, 0.f, 0.f};
#pragma unroll
        for (int kk = 0; kk < 8; ++kk) {
            bf16x8 b = *(const bf16x8*)(bbase + n * 16 * DDIM + kk * 32);
            acc = __builtin_amdgcn_mfma_f32_16x16x32_bf16(a[kk], b, acc, 0, 0, 0);
        }
        const int bin = n * 16 + (lane & 15);
        if (bin <= 128) {   // GUARD: n=8 covers bins 128..143; only 128 is real.
#pragma unroll
            for (int rr = 0; rr < 4; ++rr)
                xch[srcw][trig][lrow + rr][bin] = acc[rr];
        }
    }
    __syncthreads();

    // block reduce of (|fft_c| - |fft_t|)^2 over 16 rows x 129 bins
    {
        const int rr = t >> 4;
        float s = 0.0f;
        for (int b = (t & 15); b < NBINS; b += 16) {
            const float crc = xch[0][0][rr][b], cic = xch[0][1][rr][b];
            const float crt = xch[1][0][rr][b], cit = xch[1][1][rr][b];
            const float d = sqrtf(crc * crc + cic * cic)
                          - sqrtf(crt * crt + cit * cit);
            s += d * d;
        }
        s = wave_red(s);
        if (lane == 0) rbuf[w] = s;
    }
    __syncthreads();
    if (t == 0) {
        freq_part[blockIdx.x] = rbuf[0] + rbuf[1] + rbuf[2] + rbuf[3];
        spat_part[blockIdx.x] = sp4[0] + sp4[1] + sp4[2] + sp4[3];
    }
}

// ---------------------------------------------------------------------------
// Kernel 3: 128x128 bf16 MFMA GEMM. SWAPPED-operand MFMA (mfma(B,A)) so the
// output-row index lands in lane&15 and the reduced (column) dim is lane-
// local: epilogue row-sum = in-register adds + 2 shuffles (was 128 shuffles).
// Supertile XCD swizzle + swizzled staging + plain launch bounds unchanged.
// ---------------------------------------------------------------------------
#define BM 128
#define BN 128
#define BK 64

__global__ __launch_bounds__(256) void k_gemm(const unsigned short* __restrict__ cnb,
                                              const unsigned short* __restrict__ tnb,
                                              const int* __restrict__ sid,
                                              float* __restrict__ pall,
                                              float* __restrict__ ppos) {
    __shared__ unsigned short As[BM][BK];
    __shared__ unsigned short Bs[BN][BK];
    __shared__ float ps[2][BM][2];          // [colhalf][row][all|pos]
    __shared__ int sidI[BM], sidJ[BN];

    // Supertile XCD swizzle: xcd = bid&7 owns ib band [xcd*8, xcd*8+8).
    // Within XCD, walk 8x8 (ib x jb) supertiles -> ~1 MB working set per
    // supertile, fits 4 MB per-XCD L2. Bijective (4096%8==0).
    const int bid = blockIdx.x;
    const int xcd = bid & 7;
    const int q   = bid >> 3;            // 0..511
    const int grp = q >> 6;              // jb supertile group 0..7
    const int r   = q & 63;
    const int ib  = xcd * 8 + (r >> 3);
    const int jb  = grp * 8 + (r & 7);
    const int i0  = ib * BM;
    const int j0  = jb * BN;

    const int t = threadIdx.x;
    if (t < 128) sidI[t] = sid[i0 + t];
    else         sidJ[t - 128] = sid[j0 + t - 128];

    const int wid  = t >> 6;
    const int lane = t & 63;
    const int wrow = (wid >> 1) * 64;
    const int wcol = (wid & 1) * 64;
    const int rx   = lane & 7;

    f32x4 acc[4][4];
#pragma unroll
    for (int m = 0; m < 4; ++m)
#pragma unroll
        for (int n = 0; n < 4; ++n)
            acc[m][n] = (f32x4){0.f, 0.f, 0.f, 0.f};

    for (int kt = 0; kt < DDIM / BK; ++kt) {
        // stage: linear LDS dest, inverse-swizzled global source
#pragma unroll
        for (int it = 0; it < 4; ++it) {
            const int g  = it * 256 + t;          // 16B granule 0..1023
            const int rr = g >> 3;
            const int sl = g & 7;
            const int sc = ((sl ^ (rr & 7)) << 3);
            gload_lds16(cnb + (i0 + rr) * DDIM + kt * BK + sc,
                        (char*)&As[0][0] + g * 16);
            gload_lds16(tnb + (j0 + rr) * DDIM + kt * BK + sc,
                        (char*)&Bs[0][0] + g * 16);
        }
        __syncthreads();   // drains vmcnt before reads
#pragma unroll
        for (int kk = 0; kk < BK / 32; ++kk) {
            const int kslot = kk * 4 + (lane >> 4);
            bf16x8 af[4], bfr[4];
#pragma unroll
            for (int m = 0; m < 4; ++m) {
                const int row = wrow + m * 16 + (lane & 15);
                af[m] = *(const bf16x8*)((const char*)&As[0][0]
                          + row * 128 + ((kslot ^ rx) << 4));
            }
#pragma unroll
            for (int n = 0; n < 4; ++n) {
                const int row = wcol + n * 16 + (lane & 15);
                bfr[n] = *(const bf16x8*)((const char*)&Bs[0][0]
                          + row * 128 + ((kslot ^ rx) << 4));
            }
            // SWAPPED: acc[m][n][i][j] = tn-tile(n) x cn-tile(m) -> D layout:
            // lane&15 = cn row (output row), in-lane r = tn col.
#pragma unroll
            for (int m = 0; m < 4; ++m)
#pragma unroll
                for (int n = 0; n < 4; ++n)
                    acc[m][n] = __builtin_amdgcn_mfma_f32_16x16x32_bf16(
                        bfr[n], af[m], acc[m][n], 0, 0, 0);
        }
        __syncthreads();   // all reads done before next stage overwrites
    }

    // epilogue: exp2 + mask accumulated IN REGISTERS over (n, r); only the
    // 4 lane-groups (lane>>4) need cross-lane reduce: shfl_xor 16, 32.
    const float C = (1.0f / 0.07f) * 1.442695041f;   // invT * log2(e)
#pragma unroll
    for (int m = 0; m < 4; ++m) {
        const int rowm = wrow + m * 16 + (lane & 15);   // this lane's row
        const int si = sidI[rowm];
        float ra = 0.0f, rp = 0.0f;
#pragma unroll
        for (int n = 0; n < 4; ++n) {
            const int cb = wcol + n * 16 + ((lane >> 4) << 2);
            const int4 sj4 = *(const int4*)&sidJ[cb];
            float e0 = exp2f(acc[m][n][0] * C);
            float e1 = exp2f(acc[m][n][1] * C);
            float e2 = exp2f(acc[m][n][2] * C);
            float e3 = exp2f(acc[m][n][3] * C);
            ra += e0 + e1 + e2 + e3;
            rp += (si == sj4.x) ? e0 : 0.0f;
            rp += (si == sj4.y) ? e1 : 0.0f;
            rp += (si == sj4.z) ? e2 : 0.0f;
            rp += (si == sj4.w) ? e3 : 0.0f;
        }
        ra += __shfl_xor(ra, 16, 64);
        ra += __shfl_xor(ra, 32, 64);
        rp += __shfl_xor(rp, 16, 64);
        rp += __shfl_xor(rp, 32, 64);
        if (lane < 16) {
            ps[wid & 1][wrow + m * 16 + lane][0] = ra;
            ps[wid & 1][wrow + m * 16 + lane][1] = rp;
        }
    }
    __syncthreads();
    if (t < BM) {
        const float sa = ps[0][t][0] + ps[1][t][0];
        const float sp = ps[0][t][1] + ps[1][t][1];
        pall[jb * NROWS + i0 + t] = sa;
        ppos[jb * NROWS + i0 + t] = sp;
    }
}

// ---------------------------------------------------------------------------
// Kernel 4: per-row sum over 64 j-block partials + log terms.
// ---------------------------------------------------------------------------
__global__ __launch_bounds__(256) void k_red(const float* __restrict__ pall,
                                             const float* __restrict__ ppos,
                                             float* __restrict__ contrib) {
    __shared__ float red[256];
    const int row = blockIdx.x * 256 + threadIdx.x;
    float sa = 0.0f, sp = 0.0f;
    for (int jb = 0; jb < 64; ++jb) {
        sa += pall[jb * NROWS + row];
        sp += ppos[jb * NROWS + row];
    }
    red[threadIdx.x] = logf(sa + 1e-8f) - logf(sp);
    __syncthreads();
#pragma unroll
    for (int s = 128; s > 0; s >>= 1) {
        if (threadIdx.x < s) red[threadIdx.x] += red[threadIdx.x + s];
        __syncthreads();
    }
    if (threadIdx.x == 0) contrib[blockIdx.x] = red[0];
}

// ---------------------------------------------------------------------------
// Kernel 5: fold all partials -> 4 outputs
// ---------------------------------------------------------------------------
__global__ __launch_bounds__(256) void k_final(const float* __restrict__ spat_part,
                                               const float* __restrict__ freq_part,
                                               const float* __restrict__ contrib,
                                               float* __restrict__ out) {
    __shared__ float reda[256], redb[256], redc[256];
    float a = 0.0f, b = 0.0f, c = 0.0f;
    for (int i = threadIdx.x; i < 512; i += 256) {
        a += spat_part[i];
        b += freq_part[i];
    }
    if (threadIdx.x < 32) c = contrib[threadIdx.x];
    reda[threadIdx.x] = a; redb[threadIdx.x] = b; redc[threadIdx.x] = c;
    __syncthreads();
#pragma unroll
    for (int s = 128; s > 0; s >>= 1) {
        if (threadIdx.x < s) {
            reda[threadIdx.x] += reda[threadIdx.x + s];
            redb[threadIdx.x] += redb[threadIdx.x + s];
            redc[threadIdx.x] += redc[threadIdx.x + s];
        }
        __syncthreads();
    }
    if (threadIdx.x == 0) {
        float spatial = reda[0] / (float)(NROWS * DDIM);
        float frequency = redb[0] / (float)(NROWS * NBINS);
        float contrastive = redc[0] / (float)NROWS;
        out[0] = spatial + frequency + 0.5f * contrastive;
        out[1] = spatial;
        out[2] = frequency;
        out[3] = contrastive;
    }
}

// ---------------------------------------------------------------------------
extern "C" void kernel_launch(void* const* d_in, const int* in_sizes, int n_in,
                              void* d_out, int out_size, void* d_ws, size_t ws_size,
                              hipStream_t stream) {
    const float* clean = (const float*)d_in[0];
    const float* turb  = (const float*)d_in[1];
    const int*   sids  = (const int*)d_in[2];

    char* ws = (char*)d_ws;
    unsigned short* cnb    = (unsigned short*)ws;                      // 4 MB
    unsigned short* tnb    = (unsigned short*)(ws + 4194304);          // 4 MB
    unsigned short* basisT = (unsigned short*)(ws + 8388608);          // 147 KB
    float* pall      = (float*)(ws + 8650752);                         // 2 MB
    float* ppos      = (float*)(ws + 10747904);                        // 2 MB
    float* spat_part = (float*)(ws + 12845056);                        // 2 KB
    float* freq_part = (float*)(ws + 12849152);                        // 2 KB
    float* contrib   = (float*)(ws + 12853248);                        // 128 B

    hipLaunchKernelGGL(k_basis, dim3(288), dim3(256), 0, stream, basisT);
    hipLaunchKernelGGL(k_prep, dim3(NROWS / 16), dim3(256), 0, stream,
                       clean, turb, basisT, cnb, tnb, spat_part, freq_part);
    hipLaunchKernelGGL(k_gemm, dim3(4096), dim3(256), 0, stream,
                       cnb, tnb, sids, pall, ppos);
    hipLaunchKernelGGL(k_red, dim3(NROWS / 256), dim3(256), 0, stream,
                       pall, ppos, contrib);
    hipLaunchKernelGGL(k_final, dim3(1), dim3(256), 0, stream,
                       spat_part, freq_part, contrib, (float*)d_out);
}